// Round 6
// baseline (77.613 us; speedup 1.0000x reference)
//
#include <hip/hip_runtime.h>

// SipmResponse: B=4, N=1024, H=W=48, T=1024, HID=16. Output (48,48,1024) fp32.
//
// Sparsity:
//  - spatial: baseline=exp(-0.01*r2) -> cutoff r2<2500 (50mm), residual <1.4e-11
//  - temporal: gaussian sigma=1 -> cutoff |t-z|<6, residual <1.6e-8 per pair
// Threshold is 2.4e-4 absolute; both cutoffs are >4 orders below.
//
// R6: SINGLE dispatch (R5 post-mortem: two structural prep-side fixes bought
// only ~1us each -> the ~25us floor was 3 stream-serialized dispatches + prep
// exec + inter-kernel drains, not hot-kernel interior). One block per sensor:
//   1. stage MLP weights to LDS
//   2. scan all 4096 electrons (16 coalesced float2 iters), compact in-range
//      indices (mean ~146) to LDS
//   3. packed per-survivor radial MLP (tanh via v_exp+v_rcp -- R2-verified
//      accuracy 1.5e-5; default launch bounds: R2's spill came from the
//      (256,3) VGPR cap, R1 ran 196 VGPR spill-free) -> scatter {z,resp}
//      into 64 LDS time-buckets of 16 ticks
//   4. phase C: thread owns 4 ticks, scans <=2 overlapping buckets,
//      2-exp recurrence for the 4-tick gaussian column
//   5. one coalesced float4 row write (full coverage, no output memset)
// No d_ws use, no memset, no LUT kernel, no bin kernel.

constexpr int NE   = 4096;
constexpr int T_   = 1024;
constexpr int NWID = 48;
constexpr int HID  = 16;
constexpr int MAXL = 512;   // survivor capacity (mean 146, sigma ~12)
constexpr int NB   = 64;    // time buckets (16 ticks each)
constexpr int CAP  = 17;    // per-bucket capacity (mean 2.3); 17 breaks stride

__device__ __forceinline__ float tanh_fast(float x) {
    float e2 = __expf(2.0f * x);
    return (e2 - 1.0f) * __builtin_amdgcn_rcpf(e2 + 1.0f);
}

__global__ __launch_bounds__(256) void sipm_kernel(
    const float* __restrict__ el_photons,   // (4096)
    const float* __restrict__ xy,           // (4096,2)
    const float* __restrict__ zpos,         // (4096)
    const float* __restrict__ W1, const float* __restrict__ b1,
    const float* __restrict__ W2, const float* __restrict__ b2,
    const float* __restrict__ W3, const float* __restrict__ b3,
    const float* __restrict__ amplitude,
    float* __restrict__ out)                // (2304, 1024)
{
    const int tid = threadIdx.x;
    const int s   = blockIdx.x;
    const int h   = s / NWID;
    const int w   = s - h * NWID;
    const float sx = ((float)h - 23.5f) * 10.0f;   // exact sensor coords
    const float sy = ((float)w - 23.5f) * 10.0f;

    __shared__ float sW1[HID], sb1[HID], sW2[HID * HID], sb2[HID], sW3[HID];
    __shared__ float sMisc[2];            // {b3, exp(amplitude)}
    __shared__ int   sCnt;
    __shared__ int   eL[MAXL];
    __shared__ int   bCnt[NB];
    __shared__ float zB[NB * CAP];
    __shared__ float rB[NB * CAP];

    sW2[tid] = W2[tid];                   // exactly 256 threads
    if (tid < HID) {
        sW1[tid] = W1[tid];
        sb1[tid] = b1[tid];
        sb2[tid] = b2[tid];
        sW3[tid] = W3[tid];
    }
    if (tid < NB) bCnt[tid] = 0;
    if (tid == 0) {
        sMisc[0] = b3[0];
        sMisc[1] = __expf(amplitude[0]);
        sCnt = 0;
    }
    __syncthreads();

    // ---- scan + compact ----
    const float2* __restrict__ xy2 = (const float2*)xy;
    for (int e = tid; e < NE; e += 256) {
        float2 p = xy2[e];
        float dx = p.x - sx, dy = p.y - sy;
        float r2 = dx * dx + dy * dy;
        if (r2 < 2500.0f) {
            int idx = atomicAdd(&sCnt, 1);
            if (idx < MAXL) eL[idx] = e;
        }
    }
    __syncthreads();
    const int   n   = min(sCnt, MAXL);
    const float bb3 = sMisc[0];
    const float amp = sMisc[1];

    // ---- packed per-survivor MLP -> time-bucket scatter ----
    for (int k = tid; k < n; k += 256) {
        int e = eL[k];
        float2 p = xy2[e];
        float dx = p.x - sx, dy = p.y - sy;
        float r2 = dx * dx + dy * dy;
        float r  = sqrtf(r2) * (1.0f / 500.0f);

        float h1[HID];
        #pragma unroll
        for (int j = 0; j < HID; ++j) h1[j] = tanh_fast(fmaf(r, sW1[j], sb1[j]));

        float psf = bb3;
        #pragma unroll
        for (int j = 0; j < HID; ++j) {
            float a = sb2[j];
            #pragma unroll
            for (int kk = 0; kk < HID; ++kk) a = fmaf(h1[kk], sW2[kk * HID + j], a);
            psf = fmaf(tanh_fast(a), sW3[j], psf);
        }
        float resp = amp * __expf(-0.01f * r2) * (1.0f + psf)
                   * el_photons[e] * 0.3989422804f;
        float z = zpos[e];
        int b = min(NB - 1, (int)(z * (1.0f / 16.0f)));
        int slot = atomicAdd(&bCnt[b], 1);
        if (slot < CAP) {
            zB[b * CAP + slot] = z;
            rB[b * CAP + slot] = resp;
        }
    }
    __syncthreads();

    // ---- phase C: thread owns ticks [4t,4t+3]; scan <=2 buckets ----
    const float t0 = (float)(tid * 4);
    const int blo = max(0,      (int)floorf((t0 - 6.0f) * (1.0f / 16.0f)));
    const int bhi = min(NB - 1, (int)((t0 + 9.0f) * (1.0f / 16.0f)));
    const float C1 = 0.36787944117f;   // e^-1
    float4 acc = make_float4(0.f, 0.f, 0.f, 0.f);
    for (int b = blo; b <= bhi; ++b) {
        const int cnt = min(bCnt[b], CAP);
        for (int k = 0; k < cnt; ++k) {
            float z  = zB[b * CAP + k];
            float rk = rB[b * CAP + k];
            float d0 = t0 - z;
            // E(i)=exp(-0.5*(d0+i)^2) via recurrence: 2 exp for 4 ticks
            float e0 = __expf(-0.5f * d0 * d0);
            float q  = __expf(-d0 - 0.5f);     // |d0|<=~40 in-window -> finite
            float q2 = q * C1;
            float e1 = e0 * q;
            float e2 = e1 * q2;
            float e3 = e2 * (q2 * C1);
            acc.x = fmaf(rk, e0, acc.x);
            acc.y = fmaf(rk, e1, acc.y);
            acc.z = fmaf(rk, e2, acc.z);
            acc.w = fmaf(rk, e3, acc.w);
        }
    }

    // every block writes its full row -> full coverage, no output memset
    ((float4*)(out + (size_t)s * T_))[tid] = acc;
}

extern "C" void kernel_launch(void* const* d_in, const int* in_sizes, int n_in,
                              void* d_out, int out_size, void* d_ws, size_t ws_size,
                              hipStream_t stream) {
    const float* el  = (const float*)d_in[0];
    const float* xy  = (const float*)d_in[1];
    const float* zp  = (const float*)d_in[2];
    // d_in[3] = sensor_locations: recomputed analytically in-kernel (exact)
    const float* W1  = (const float*)d_in[4];
    const float* b1  = (const float*)d_in[5];
    const float* W2  = (const float*)d_in[6];
    const float* b2  = (const float*)d_in[7];
    const float* W3  = (const float*)d_in[8];
    const float* b3  = (const float*)d_in[9];
    const float* amp = (const float*)d_in[10];
    float* out = (float*)d_out;

    sipm_kernel<<<dim3(48 * 48), dim3(256), 0, stream>>>(
        el, xy, zp, W1, b1, W2, b2, W3, b3, amp, out);
}

// Round 7
// 30.635 us; speedup vs baseline: 2.5334x; 2.5334x over previous
//
#include <hip/hip_runtime.h>

// SipmResponse: B=4, N=1024, H=W=48, T=1024, HID=16. Output (48,48,1024) fp32.
//
// Sparsity:
//  - spatial: baseline=exp(-0.01*r2) -> cutoff r2<2500 (50mm), residual <1.4e-11
//  - temporal: gaussian sigma=1 -> cutoff |t-z|<6, residual <1.6e-8 per pair
// Threshold 2.4e-4 absolute.
//
// R7: the radial MLP factor (1+psf(r)) on r in [0,0.1] (50mm cutoff) is
// ultra-smooth -> degree-10 Chebyshev captures it to ~1e-6 rel. The stiff
// exp(-0.01 r^2) is computed exactly per survivor (1 v_exp). This removes
// BOTH the in-kernel MLP (R6: VGPR 244, 2 waves/SIMD, 87us) AND the LUT
// machinery (R5: LUT global round-trip + 4KB/block LDS staging + memset +
// bin kernel).
//  1. fit_kernel (1 block, 64 thr): MLP at 11 Chebyshev nodes, 11x11 DCT,
//     coeffs scaled by exp(amplitude)*gauss_norm -> 11 floats in d_ws.
//  2. sipm_kernel (2304 blocks): coeffs via uniform s_loads; fused scan of
//     all 4096 electrons (16 coalesced float2 iters); in-range survivors
//     (mean ~146) -> sqrt + 20-FMA Clenshaw + 1 exp + {photons,z} gathers
//     -> scatter {z,resp} into 64 LDS time-buckets; phase C: thread owns
//     4 ticks, scans <=2 buckets (2-exp recurrence); one float4 row write.

constexpr int NE   = 4096;
constexpr int T_   = 1024;
constexpr int NWID = 48;
constexpr int HID  = 16;
constexpr int NB   = 64;    // time buckets (16 ticks each)
constexpr int CAP  = 17;    // per-bucket capacity (mean 2.3)
constexpr int DCH  = 10;    // Chebyshev degree
constexpr int NCH  = 11;    // nodes / coeffs

__device__ __forceinline__ float tanh_fast(float x) {
    float e2 = __expf(2.0f * x);
    return (e2 - 1.0f) * __builtin_amdgcn_rcpf(e2 + 1.0f);
}

__global__ __launch_bounds__(64) void fit_kernel(
    const float* __restrict__ W1, const float* __restrict__ b1,
    const float* __restrict__ W2, const float* __restrict__ b2,
    const float* __restrict__ W3, const float* __restrict__ b3,
    const float* __restrict__ amplitude,
    float* __restrict__ cw)                 // (NCH)
{
    __shared__ float f[NCH];
    const int j = threadIdx.x;
    const float PI = 3.14159265358979f;
    if (j < NCH) {
        float xj   = cosf(PI * (j + 0.5f) / (float)NCH);   // node in [-1,1]
        float r_mm = 25.0f * (xj + 1.0f);                   // [0,50]
        float r    = r_mm * (1.0f / 500.0f);
        float h1[HID];
        #pragma unroll
        for (int q = 0; q < HID; ++q) h1[q] = tanh_fast(fmaf(r, W1[q], b1[q]));
        float psf = b3[0];
        #pragma unroll
        for (int q = 0; q < HID; ++q) {
            float a = b2[q];
            #pragma unroll
            for (int k = 0; k < HID; ++k) a = fmaf(h1[k], W2[k * HID + q], a);
            psf = fmaf(tanh_fast(a), W3[q], psf);
        }
        f[j] = 1.0f + psf;
    }
    __syncthreads();
    if (j < NCH) {
        float s = 0.0f;
        for (int q = 0; q < NCH; ++q)
            s += f[q] * cosf(PI * (float)j * (q + 0.5f) / (float)NCH);
        float a = (j == 0) ? s * (1.0f / NCH) : s * (2.0f / NCH);
        cw[j] = a * __expf(amplitude[0]) * 0.3989422804f;
    }
}

__global__ __launch_bounds__(256) void sipm_kernel(
    const float* __restrict__ el_photons,   // (4096)
    const float* __restrict__ xy,           // (4096,2)
    const float* __restrict__ zpos,         // (4096)
    const float* __restrict__ cw,           // (NCH) chebyshev coeffs
    float* __restrict__ out)                // (2304, 1024)
{
    const int tid = threadIdx.x;
    const int s   = blockIdx.x;
    const int h   = s / NWID;
    const int w   = s - h * NWID;
    const float sx = ((float)h - 23.5f) * 10.0f;   // exact sensor coords
    const float sy = ((float)w - 23.5f) * 10.0f;

    __shared__ int   bCnt[NB];
    __shared__ float zB[NB * CAP];
    __shared__ float rB[NB * CAP];

    // coefficients: uniform addresses -> scalar loads, live in SGPRs
    float c[NCH];
    #pragma unroll
    for (int k = 0; k < NCH; ++k) c[k] = cw[k];

    if (tid < NB) bCnt[tid] = 0;
    __syncthreads();

    // ---- fused scan -> Clenshaw PSF -> time-bucket scatter ----
    const float2* __restrict__ xy2 = (const float2*)xy;
    for (int e = tid; e < NE; e += 256) {
        float2 p = xy2[e];
        float dx = p.x - sx, dy = p.y - sy;
        float r2 = dx * dx + dy * dy;
        if (r2 < 2500.0f) {
            float u  = sqrtf(r2);
            float x  = fmaf(u, 0.04f, -1.0f);       // r_mm in [0,50] -> [-1,1]
            float x2 = x + x;
            float bk1 = 0.0f, bk2 = 0.0f;
            #pragma unroll
            for (int k = DCH; k >= 1; --k) {
                float t = fmaf(x2, bk1, c[k] - bk2);
                bk2 = bk1; bk1 = t;
            }
            float pv   = fmaf(x, bk1, c[0] - bk2);  // amp*norm*(1+psf)
            float resp = __expf(-0.01f * r2) * pv * el_photons[e];
            float zz   = zpos[e];
            int b = min(NB - 1, (int)(zz * (1.0f / 16.0f)));
            int slot = atomicAdd(&bCnt[b], 1);
            if (slot < CAP) {
                zB[b * CAP + slot] = zz;
                rB[b * CAP + slot] = resp;
            }
        }
    }
    __syncthreads();

    // ---- phase C: thread owns ticks [4t,4t+3]; scan <=2 buckets ----
    const float t0 = (float)(tid * 4);
    const int blo = max(0,      (int)floorf((t0 - 6.0f) * (1.0f / 16.0f)));
    const int bhi = min(NB - 1, (int)((t0 + 9.0f) * (1.0f / 16.0f)));
    const float C1 = 0.36787944117f;   // e^-1
    float4 acc = make_float4(0.f, 0.f, 0.f, 0.f);
    for (int b = blo; b <= bhi; ++b) {
        const int cnt = min(bCnt[b], CAP);
        for (int k = 0; k < cnt; ++k) {
            float z  = zB[b * CAP + k];
            float rk = rB[b * CAP + k];
            float d0 = t0 - z;
            // E(i)=exp(-0.5*(d0+i)^2) via recurrence: 2 exp for 4 ticks
            float e0 = __expf(-0.5f * d0 * d0);
            float q  = __expf(-d0 - 0.5f);
            float q2 = q * C1;
            float e1 = e0 * q;
            float e2 = e1 * q2;
            float e3 = e2 * (q2 * C1);
            acc.x = fmaf(rk, e0, acc.x);
            acc.y = fmaf(rk, e1, acc.y);
            acc.z = fmaf(rk, e2, acc.z);
            acc.w = fmaf(rk, e3, acc.w);
        }
    }

    // every block writes its full row -> full coverage, no output memset
    ((float4*)(out + (size_t)s * T_))[tid] = acc;
}

extern "C" void kernel_launch(void* const* d_in, const int* in_sizes, int n_in,
                              void* d_out, int out_size, void* d_ws, size_t ws_size,
                              hipStream_t stream) {
    const float* el  = (const float*)d_in[0];
    const float* xy  = (const float*)d_in[1];
    const float* zp  = (const float*)d_in[2];
    // d_in[3] = sensor_locations: recomputed analytically in-kernel (exact)
    const float* W1  = (const float*)d_in[4];
    const float* b1  = (const float*)d_in[5];
    const float* W2  = (const float*)d_in[6];
    const float* b2  = (const float*)d_in[7];
    const float* W3  = (const float*)d_in[8];
    const float* b3  = (const float*)d_in[9];
    const float* amp = (const float*)d_in[10];
    float* out = (float*)d_out;
    float* cw  = (float*)d_ws;    // 11 floats

    fit_kernel<<<dim3(1), dim3(64), 0, stream>>>(
        W1, b1, W2, b2, W3, b3, amp, cw);
    sipm_kernel<<<dim3(48 * 48), dim3(256), 0, stream>>>(
        el, xy, zp, cw, out);
}

// Round 8
// 22.698 us; speedup vs baseline: 3.4194x; 1.3497x over previous
//
#include <hip/hip_runtime.h>

// SipmResponse: B=4, N=1024, H=W=48, T=1024, HID=16. Output (48,48,1024) fp32.
//
// Sparsity:
//  - spatial: baseline=exp(-0.01*r2) -> cutoff r2<2500 (50mm), residual <1.4e-11
//  - temporal: gaussian sigma=1 -> cutoff |t-z|<6, residual <1.6e-8 per pair
// Threshold 2.4e-4 absolute.
//
// R8: SINGLE dispatch, zero workspace. The degree-10 Chebyshev fit of the
// radial MLP factor (R7-verified: absmax 1.5e-5) is computed redundantly in
// EVERY block, overlapped with the electron scan:
//   init barrier
//   wave 0 lanes 0-10:  MLP at 11 Chebyshev nodes -> f[] in LDS   (latency
//   waves 1-3 (192 thr): scan 4096 electrons via float4 (2 el/load,  hides
//                        10.7 iters), compact {e, r2} to LDS        mutually)
//   barrier; lanes 0-10: 11x11 DCT (__cosf), fold exp(amp)*norm -> cw[]
//   barrier; phase B (256 thr packed): sqrt + 20-FMA Clenshaw + 1 exp +
//            {photons,z} gather -> scatter {z,resp} into 64 time buckets
//   barrier; phase C: thread owns 4 ticks, scans <=2 buckets (2-exp
//            recurrence); one coalesced float4 row write (full coverage).
// R7 post-mortem: 3 different prep pipelines all plateau ~30us; R6 proved
// dur_us ~= sum of kernel exec. This round isolates launch+fit overhead
// (removed here) from the sipm interior.

constexpr int NE   = 4096;
constexpr int T_   = 1024;
constexpr int NWID = 48;
constexpr int HID  = 16;
constexpr int MAXL = 512;   // survivor capacity (mean 146, >20 sigma)
constexpr int NB   = 64;    // time buckets (16 ticks each)
constexpr int CAP  = 17;    // per-bucket capacity (mean 2.3)
constexpr int DCH  = 10;    // Chebyshev degree
constexpr int NCH  = 11;    // nodes / coeffs

__device__ __forceinline__ float tanh_fast(float x) {
    float e2 = __expf(2.0f * x);
    return (e2 - 1.0f) * __builtin_amdgcn_rcpf(e2 + 1.0f);
}

__global__ __launch_bounds__(256) void sipm_kernel(
    const float* __restrict__ el_photons,   // (4096)
    const float* __restrict__ xy,           // (4096,2)
    const float* __restrict__ zpos,         // (4096)
    const float* __restrict__ W1, const float* __restrict__ b1,
    const float* __restrict__ W2, const float* __restrict__ b2,
    const float* __restrict__ W3, const float* __restrict__ b3,
    const float* __restrict__ amplitude,
    float* __restrict__ out)                // (2304, 1024)
{
    const int tid = threadIdx.x;
    const int s   = blockIdx.x;
    const int h   = s / NWID;
    const int w   = s - h * NWID;
    const float sx = ((float)h - 23.5f) * 10.0f;   // exact sensor coords
    const float sy = ((float)w - 23.5f) * 10.0f;
    const float PI = 3.14159265358979f;

    __shared__ float f[NCH];
    __shared__ float cw[NCH];
    __shared__ int   sCnt;
    __shared__ int   eL[MAXL];
    __shared__ float r2L[MAXL];
    __shared__ int   bCnt[NB];
    __shared__ float zB[NB * CAP];
    __shared__ float rB[NB * CAP];

    if (tid < NB) bCnt[tid] = 0;
    if (tid == 0) sCnt = 0;
    __syncthreads();

    if (tid < NCH) {
        // ---- wave 0: Chebyshev-node MLP (overlaps the scan below) ----
        float xj   = __cosf(PI * ((float)tid + 0.5f) / (float)NCH); // [-1,1]
        float r    = 25.0f * (xj + 1.0f) * (1.0f / 500.0f);         // [0,0.1]
        float h1[HID];
        #pragma unroll
        for (int q = 0; q < HID; ++q) h1[q] = tanh_fast(fmaf(r, W1[q], b1[q]));
        float psf = b3[0];
        #pragma unroll
        for (int q = 0; q < HID; ++q) {
            float a = b2[q];
            #pragma unroll
            for (int k = 0; k < HID; ++k) a = fmaf(h1[k], W2[k * HID + q], a);
            psf = fmaf(tanh_fast(a), W3[q], psf);
        }
        f[tid] = 1.0f + psf;
    } else if (tid >= 64) {
        // ---- waves 1-3: scan + compact {e, r2} (float4 = 2 electrons) ----
        const float4* __restrict__ xy4 = (const float4*)xy;   // 2048 entries
        for (int i = tid - 64; i < NE / 2; i += 192) {
            float4 q = xy4[i];
            float dx0 = q.x - sx, dy0 = q.y - sy;
            float r2a = dx0 * dx0 + dy0 * dy0;
            if (r2a < 2500.0f) {
                int idx = atomicAdd(&sCnt, 1);
                if (idx < MAXL) { eL[idx] = 2 * i;     r2L[idx] = r2a; }
            }
            float dx1 = q.z - sx, dy1 = q.w - sy;
            float r2b = dx1 * dx1 + dy1 * dy1;
            if (r2b < 2500.0f) {
                int idx = atomicAdd(&sCnt, 1);
                if (idx < MAXL) { eL[idx] = 2 * i + 1; r2L[idx] = r2b; }
            }
        }
    }
    __syncthreads();

    if (tid < NCH) {
        // ---- 11x11 DCT -> scaled Chebyshev coeffs ----
        float acc = 0.0f;
        #pragma unroll
        for (int q = 0; q < NCH; ++q)
            acc += f[q] * __cosf(PI * (float)tid * ((float)q + 0.5f) / (float)NCH);
        float a = (tid == 0) ? acc * (1.0f / NCH) : acc * (2.0f / NCH);
        cw[tid] = a * __expf(amplitude[0]) * 0.3989422804f;
    }
    __syncthreads();

    const int n = min(sCnt, MAXL);
    float c[NCH];
    #pragma unroll
    for (int k = 0; k < NCH; ++k) c[k] = cw[k];   // broadcast LDS reads

    // ---- phase B: packed Clenshaw + exp + gather -> time-bucket scatter ----
    for (int k = tid; k < n; k += 256) {
        int   e  = eL[k];
        float r2 = r2L[k];
        float u  = sqrtf(r2);
        float x  = fmaf(u, 0.04f, -1.0f);          // r_mm [0,50] -> [-1,1]
        float x2 = x + x;
        float bk1 = 0.0f, bk2 = 0.0f;
        #pragma unroll
        for (int q = DCH; q >= 1; --q) {
            float t = fmaf(x2, bk1, c[q] - bk2);
            bk2 = bk1; bk1 = t;
        }
        float pv   = fmaf(x, bk1, c[0] - bk2);     // amp*norm*(1+psf)
        float resp = __expf(-0.01f * r2) * pv * el_photons[e];
        float zz   = zpos[e];
        int b = min(NB - 1, (int)(zz * (1.0f / 16.0f)));
        int slot = atomicAdd(&bCnt[b], 1);
        if (slot < CAP) {
            zB[b * CAP + slot] = zz;
            rB[b * CAP + slot] = resp;
        }
    }
    __syncthreads();

    // ---- phase C: thread owns ticks [4t,4t+3]; scan <=2 buckets ----
    const float t0 = (float)(tid * 4);
    const int blo = max(0,      (int)floorf((t0 - 6.0f) * (1.0f / 16.0f)));
    const int bhi = min(NB - 1, (int)((t0 + 9.0f) * (1.0f / 16.0f)));
    const float C1 = 0.36787944117f;   // e^-1
    float4 acc = make_float4(0.f, 0.f, 0.f, 0.f);
    for (int b = blo; b <= bhi; ++b) {
        const int cnt = min(bCnt[b], CAP);
        for (int k = 0; k < cnt; ++k) {
            float z  = zB[b * CAP + k];
            float rk = rB[b * CAP + k];
            float d0 = t0 - z;
            // E(i)=exp(-0.5*(d0+i)^2) via recurrence: 2 exp for 4 ticks
            float e0 = __expf(-0.5f * d0 * d0);
            float q  = __expf(-d0 - 0.5f);
            float q2 = q * C1;
            float e1 = e0 * q;
            float e2 = e1 * q2;
            float e3 = e2 * (q2 * C1);
            acc.x = fmaf(rk, e0, acc.x);
            acc.y = fmaf(rk, e1, acc.y);
            acc.z = fmaf(rk, e2, acc.z);
            acc.w = fmaf(rk, e3, acc.w);
        }
    }

    // every block writes its full row -> full coverage, no output memset
    ((float4*)(out + (size_t)s * T_))[tid] = acc;
}

extern "C" void kernel_launch(void* const* d_in, const int* in_sizes, int n_in,
                              void* d_out, int out_size, void* d_ws, size_t ws_size,
                              hipStream_t stream) {
    const float* el  = (const float*)d_in[0];
    const float* xy  = (const float*)d_in[1];
    const float* zp  = (const float*)d_in[2];
    // d_in[3] = sensor_locations: recomputed analytically in-kernel (exact)
    const float* W1  = (const float*)d_in[4];
    const float* b1  = (const float*)d_in[5];
    const float* W2  = (const float*)d_in[6];
    const float* b2  = (const float*)d_in[7];
    const float* W3  = (const float*)d_in[8];
    const float* b3  = (const float*)d_in[9];
    const float* amp = (const float*)d_in[10];
    float* out = (float*)d_out;

    sipm_kernel<<<dim3(48 * 48), dim3(256), 0, stream>>>(
        el, xy, zp, W1, b1, W2, b2, W3, b3, amp, out);
}